// Round 10
// baseline (300.295 us; speedup 1.0000x reference)
//
#include <hip/hip_runtime.h>
#include <stdint.h>

#define DEV __device__ __forceinline__

typedef float f32x4 __attribute__((ext_vector_type(4)));
typedef short s16x8 __attribute__((ext_vector_type(8)));
typedef unsigned int u32x4 __attribute__((ext_vector_type(4)));
typedef unsigned int u32x2 __attribute__((ext_vector_type(2)));

static constexpr int HM = 128, WM = 128;   // logical H,W
static constexpr int HP = 130, WP = 130;   // padded H,W

DEV unsigned short f2bf(float f) {
  unsigned int u = __float_as_uint(f);
  return (unsigned short)((u + 0x7fffu + ((u >> 16) & 1u)) >> 16);  // RNE
}
DEV float bf2f(unsigned short s) { return __uint_as_float(((unsigned int)s) << 16); }

DEV void gll16(const void* g, void* l) {
  __builtin_amdgcn_global_load_lds((const unsigned int*)g, (unsigned int*)l, 16, 0, 0);
}
DEV void waitvmc(int n) {  // constant-folds under full unroll
  if (n == 0)      asm volatile("s_waitcnt vmcnt(0)" ::: "memory");
  else if (n == 1) asm volatile("s_waitcnt vmcnt(1)" ::: "memory");
  else if (n == 2) asm volatile("s_waitcnt vmcnt(2)" ::: "memory");
  else if (n == 3) asm volatile("s_waitcnt vmcnt(3)" ::: "memory");
  else if (n == 4) asm volatile("s_waitcnt vmcnt(4)" ::: "memory");
  else if (n == 5) asm volatile("s_waitcnt vmcnt(5)" ::: "memory");
  else if (n == 7) asm volatile("s_waitcnt vmcnt(7)" ::: "memory");
  else             asm volatile("s_waitcnt vmcnt(0)" ::: "memory");
}

// ---------------- scatter: points -> padded channels-last C=32 grid + occ masks ----------------
__global__ __launch_bounds__(256)
void scatter_k(const float* __restrict__ vf, const int* __restrict__ co,
               unsigned short* __restrict__ x,
               unsigned char* __restrict__ o0, unsigned char* __restrict__ o1,
               unsigned char* __restrict__ o2, unsigned char* __restrict__ o3,
               int npts) {
  int i = blockIdx.x * 256 + threadIdx.x;
  if (i >= npts) return;
  int d = co[i * 4 + 1], h = co[i * 4 + 2], w = co[i * 4 + 3];
  unsigned short* dst = x + (size_t)(((d + 1) * HP + (h + 1)) * WP + (w + 1)) * 32;
#pragma unroll
  for (int c = 0; c < 16; ++c) dst[c] = f2bf(vf[i * 16 + c]);  // ch 16..31 stay zero (memset)
  int hw = h * WM + w;
  o0[d * (HM * WM) + hw] = 1;
  o1[(d >> 1) * (HM * WM) + hw] = 1;
  o2[(d >> 2) * (HM * WM) + hw] = 1;
  o3[(d >> 3) * (HM * WM) + hw] = 1;
}

// ---------------- fused weight repack: f32 [co][ci][27] -> bf16 [tap][co][ci_dst] ----------------
__global__ __launch_bounds__(256)
void wcvt_all_k(const float* s0, const float* s1, const float* s2, const float* s3,
                const float* s4, const float* s5, const float* s6, const float* s7,
                unsigned short* __restrict__ dst) {
  int t = blockIdx.x * 256 + threadIdx.x;
  const int CIs[8] = {16, 32, 64, 64, 64, 64, 64, 64};
  const int CId[8] = {32, 32, 64, 64, 64, 64, 64, 64};
  const int COa[8] = {32, 64, 64, 64, 64, 64, 64, 64};
  const float* srcs[8] = {s0, s1, s2, s3, s4, s5, s6, s7};
  int start = 0;
#pragma unroll
  for (int i = 0; i < 8; ++i) {
    int sz = 27 * COa[i] * CId[i];
    if (t >= start && t < start + sz) {
      int l = t - start;
      int ci = l % CId[i];
      int r = l / CId[i];
      int cco = r % COa[i];
      int tap = r / COa[i];
      float v = (ci < CIs[i]) ? srcs[i][(cco * CIs[i] + ci) * 27 + tap] : 0.0f;
      dst[t] = f2bf(v);
    }
    start += sz;
  }
}

// ---------------- conv 3x3x3 implicit-GEMM, MFMA bf16, rolling-row pipeline + occ j-skip ----------------
// Identical to the 276.5µs build plus: wave-uniform j-fragment occupancy skip. A j-frag's 16
// output voxels all unoccupied -> its b-read + MFMAs are skipped (epilogue writes 0 anyway:
// bit-exact). Skip rate ~45% at occ0 (4.8% occupancy), ~20% at occ1, ~3% at occ2.
template <int CI, int CO, int ROWS>
__global__ __launch_bounds__(512, 4)
void conv_k(const unsigned short* __restrict__ xin, unsigned short* __restrict__ xout,
            const unsigned short* __restrict__ wt, const unsigned char* __restrict__ occ,
            int D) {
  constexpr int SLOTS = CI / 8;      // 16B slots per voxel
  constexpr int MSK = SLOTS - 1;
  constexpr int CIB = CI / 32;       // K blocks of 32
  constexpr int NM = CO / 16;        // m-fragments
  constexpr int J = ROWS;            // voxel fragments per wave
  constexpr int XROWS = ROWS + 2;    // x window rows
  constexpr int RXI = (128 * SLOTS) / 512;     // gll instr per x row per thread (1 or 2)
  constexpr int NCW = 3 * CO * SLOTS;          // w chunks per tap-triple
  constexpr int KW = (NCW + 511) / 512;        // gll instr per w stage (wrap-dup if ragged)
  constexpr int NA = 2 * RXI + KW;             // vmcnt at kh=0
  constexpr int NB = RXI + KW;                 // vmcnt at kh=1,2 (kd<2)
  constexpr int WOFF = 3 * CO * CI;            // shorts per w buffer
  __shared__ __align__(16) unsigned short xs[XROWS * 130 * CI];
  __shared__ __align__(16) unsigned short wls[2 * WOFF];

  int nb = gridDim.x;  // divisible by 8
  int bid = blockIdx.x;
  int blk = (bid & 7) * (nb >> 3) + (bid >> 3);  // XCD-chunked swizzle (bijective)
  int tid = threadIdx.x;
  constexpr int HBLK = 128 / ROWS;
  int d = blk / HBLK, hb = blk - (blk / HBLK) * HBLK;
  int h0 = hb * ROWS;  // padded top row of x window; output padded rows h0+1..h0+ROWS
  int lane = tid & 63, wv = tid >> 6, ln = lane & 15, lg = lane >> 4;

  auto issueX = [&](int kd, int ri) {
#pragma unroll
    for (int i = 0; i < RXI; ++i) {
      int c = i * 512 + tid;                    // c over 128*SLOTS interior chunks
      int vcol = 1 + c / SLOTS;
      int sl = c - (c / SLOTS) * SLOTS;
      int v = ri * 130 + vcol;
      int ss = sl ^ (v & MSK);
      const unsigned short* g =
          xin + ((size_t)((d + kd) * HP + (h0 + ri)) * WP + vcol) * CI + ss * 8;
      gll16(g, xs + (size_t)(ri * 130 + 1) * CI + (size_t)c * 8);
    }
  };
  auto issueW = [&](int kd, int kh, unsigned short* wbuf) {
#pragma unroll
    for (int i = 0; i < KW; ++i) {
      int c = i * 512 + tid;
      if (c >= NCW) c -= NCW;  // wrap-duplicate (benign; keeps vmcnt uniform)
      int u = c / SLOTS, sl = c - (c / SLOTS) * SLOTS;
      int kw = u / CO, cc = u - kw * CO;
      int ss = sl ^ (u & MSK);
      const unsigned short* g =
          wt + ((size_t)((kd * 3 + kh) * 3 + kw) * CO + cc) * CI + ss * 8;
      gll16(g, wbuf + (size_t)c * 8);
    }
  };

  // ---- prologue ----
  // 1) output-halo zero (global stores FIRST -> oldest in vmcnt queue, folded into waits)
  {
    constexpr int CH8 = CO / 8;
    int hv = 2 * HP * WP + D * (2 * WP + 2 * HM);
    int tot8 = hv * CH8;
    int per = (tot8 + nb - 1) / nb;
    int base = blk * per, lim = base + per;
    if (lim > tot8) lim = tot8;
    for (int c = base + tid; c < lim; c += 512) {
      int i = c / CH8, sub = c - (c / CH8) * CH8;
      int p, hh, ww;
      if (i < 2 * HP * WP) {
        p = (i >= HP * WP) ? (D + 1) : 0;
        int rem = i - ((i >= HP * WP) ? HP * WP : 0);
        hh = rem / WP; ww = rem - hh * WP;
      } else {
        constexpr int PH = 2 * WP + 2 * HM;
        int j2 = i - 2 * HP * WP;
        p = j2 / PH + 1;
        int r2 = j2 - (p - 1) * PH;
        if (r2 < 2 * WP) { hh = (r2 >= WP) ? (HP - 1) : 0; ww = r2 % WP; }
        else { int r3 = r2 - 2 * WP; hh = 1 + (r3 & 127); ww = (r3 < HM) ? 0 : (WP - 1); }
      }
      *(u32x4*)(xout + ((size_t)(p * HP + hh) * WP + ww) * CO + sub * 8) = (u32x4)0u;
    }
  }
  // 2) first x rows + first w stage
  issueX(0, 0);
  issueX(0, 1);
  issueW(0, 0, wls);
  // 3) x-window halo columns (voxel cols 0,129) are always zero: ds_write once, never gll'd
  for (int t = tid; t < XROWS * 2 * SLOTS; t += 512) {
    int ri = t / (2 * SLOTS);
    int r2 = t - ri * 2 * SLOTS;
    int colv = (r2 >= SLOTS) ? 129 : 0;
    int sl = r2 & MSK;
    *(u32x4*)(xs + (size_t)(ri * 130 + colv) * CI + sl * 8) = (u32x4)0u;
  }
  // 4) occupancy mask + wave-uniform j-activity (16 voxels share one decision)
  float on[J];
  bool act[J];
#pragma unroll
  for (int j = 0; j < J; ++j) {
    int vox = wv * (16 * J) + j * 16 + ln;
    on[j] = occ[(d * HM + (h0 + (vox >> 7))) * WM + (vox & 127)] ? 1.0f : 0.0f;
    act[j] = __ballot(on[j] != 0.0f) != 0ULL;
  }
  asm volatile("s_waitcnt lgkmcnt(0)" ::: "memory");  // halo ds_writes done

  f32x4 acc[NM][J];
#pragma unroll
  for (int m = 0; m < NM; ++m)
#pragma unroll
    for (int j = 0; j < J; ++j) acc[m][j] = (f32x4)0.0f;

  // ---- 9 steps: (kd,kh), fully unrolled ----
#pragma unroll
  for (int s = 0; s < 9; ++s) {
    int kd = s / 3, kh = s - 3 * kd;
    unsigned short* wnext = wls + ((s + 1) & 1) * WOFF;
    // issue phase: refill slots freed by M(s-1), prefetch W(s+1)
    if (kh == 0) {
#pragma unroll
      for (int ri = 2; ri < XROWS; ++ri) issueX(kd, ri);
      issueW(kd, 1, wnext);
    } else if (kh == 1) {
      if (kd < 2) issueX(kd + 1, 0);
      issueW(kd, 2, wnext);
    } else {
      if (kd < 2) {
        issueX(kd + 1, 1);
        issueW(kd + 1, 0, wnext);
      }
    }
    __builtin_amdgcn_sched_barrier(0);
    // wait for M(s) deps (counted; never drains the prefetch queue mid-loop)
    if (kh == 0)      waitvmc(NA);
    else if (kh == 1) waitvmc(kd < 2 ? NB : KW);
    else              waitvmc(kd < 2 ? NB : 0);
    __builtin_amdgcn_sched_barrier(0);
    __builtin_amdgcn_s_barrier();
    __builtin_amdgcn_sched_barrier(0);
    // ---- MFMA phase (occ-skipped j-frags) ----
    const unsigned short* wc = wls + (s & 1) * WOFF;
    __builtin_amdgcn_s_setprio(1);
#pragma unroll
    for (int kw = 0; kw < 3; ++kw) {
#pragma unroll
      for (int cb = 0; cb < CIB; ++cb) {
        int slot = cb * 4 + lg;
        s16x8 a[NM];
#pragma unroll
        for (int m = 0; m < NM; ++m) {
          int u = kw * CO + m * 16 + ln;
          a[m] = *(const s16x8*)(wc + ((size_t)u * SLOTS + (slot ^ (u & MSK))) * 8);
        }
#pragma unroll
        for (int j = 0; j < J; ++j) {
          if (act[j]) {  // wave-uniform branch
            int vox = wv * (16 * J) + j * 16 + ln;
            int v = ((vox >> 7) + kh) * 130 + (vox & 127) + kw;
            s16x8 b = *(const s16x8*)(xs + ((size_t)v * SLOTS + (slot ^ (v & MSK))) * 8);
#pragma unroll
            for (int m = 0; m < NM; ++m)
              acc[m][j] = __builtin_amdgcn_mfma_f32_16x16x32_bf16(a[m], b, acc[m][j], 0, 0, 0);
          }
        }
      }
    }
    __builtin_amdgcn_s_setprio(0);
    __builtin_amdgcn_sched_barrier(0);
    if (s < 8) __builtin_amdgcn_s_barrier();  // readers done before slots are re-written
  }

  // ---- epilogue: masked relu -> bf16. D-frag: col=lane&15 -> voxel, row=lg*4+r -> co ----
#pragma unroll
  for (int j = 0; j < J; ++j) {
    int vox = wv * (16 * J) + j * 16 + ln;
    int r = vox >> 7, w2 = vox & 127;
    unsigned short* dst = xout + ((size_t)((d + 1) * HP + (h0 + r + 1)) * WP + (w2 + 1)) * CO;
#pragma unroll
    for (int m = 0; m < NM; ++m) {
      unsigned short q0 = f2bf(fmaxf(acc[m][j][0], 0.0f) * on[j]);
      unsigned short q1 = f2bf(fmaxf(acc[m][j][1], 0.0f) * on[j]);
      unsigned short q2 = f2bf(fmaxf(acc[m][j][2], 0.0f) * on[j]);
      unsigned short q3 = f2bf(fmaxf(acc[m][j][3], 0.0f) * on[j]);
      u32x2 pv;
      pv.x = (unsigned int)q0 | ((unsigned int)q1 << 16);
      pv.y = (unsigned int)q2 | ((unsigned int)q3 << 16);
      *(u32x2*)&dst[m * 16 + lg * 4] = pv;
    }
  }
}

// ---------------- spatial 3x3x3 maxpool, stride (2,1,1), occ-masked, separable ----------------
template <int C>
__global__ __launch_bounds__(256)
void pool_sp_k(const unsigned short* __restrict__ xin, unsigned short* __restrict__ xout,
               const unsigned char* __restrict__ oc, int Dout) {
  constexpr int CH = C / 8;
  __shared__ __align__(16) unsigned short vm[WP * C];
  int row = blockIdx.x;
  int bh = row % HP, bdo = row / HP;
  int outRow = (bdo * HP + bh) * WP * C;
  int tid = threadIdx.x;
  if (bdo == 0 || bdo == Dout + 1 || bh == 0 || bh == HP - 1) {
    for (int i = tid; i < WP * C; i += 256) xout[outRow + i] = 0;
    return;
  }
  int dp = bdo - 1, h = bh - 1;

  for (int idx = tid; idx < WP * CH; idx += 256) {
    int w = idx / CH, c8 = idx - w * CH;
    float mx[8];
#pragma unroll
    for (int q = 0; q < 8; ++q) mx[q] = 0.0f;
#pragma unroll
    for (int dd = 0; dd < 3; ++dd)
#pragma unroll
      for (int hh = 0; hh < 3; ++hh) {
        const unsigned short* p =
            xin + ((size_t)((2 * dp + dd) * HP + (h + hh)) * WP + w) * C + c8 * 8;
        u32x4 v = *(const u32x4*)p;
        const unsigned short* u = (const unsigned short*)&v;
#pragma unroll
        for (int q = 0; q < 8; ++q) mx[q] = fmaxf(mx[q], bf2f(u[q]));
      }
    unsigned short o[8];
#pragma unroll
    for (int q = 0; q < 8; ++q) o[q] = f2bf(mx[q]);
    *(u32x4*)&vm[w * C + c8 * 8] = *(const u32x4*)o;
  }
  __syncthreads();

  for (int idx = tid; idx < WM * CH; idx += 256) {
    int w = idx / CH, c8 = idx - w * CH;
    float mx[8];
#pragma unroll
    for (int q = 0; q < 8; ++q) mx[q] = 0.0f;
#pragma unroll
    for (int ww = 0; ww < 3; ++ww) {
      u32x4 v = *(const u32x4*)&vm[(w + ww) * C + c8 * 8];
      const unsigned short* u = (const unsigned short*)&v;
#pragma unroll
      for (int q = 0; q < 8; ++q) mx[q] = fmaxf(mx[q], bf2f(u[q]));
    }
    bool on = oc[(dp * HM + h) * WM + w] != 0;
    unsigned short o[8];
#pragma unroll
    for (int q = 0; q < 8; ++q) o[q] = on ? f2bf(mx[q]) : (unsigned short)0;
    *(u32x4*)(xout + outRow + (w + 1) * C + c8 * 8) = *(const u32x4*)o;
  }
  for (int i = tid; i < 2 * C; i += 256) {
    int s = i / C, c = i - (i / C) * C;
    xout[outRow + (s ? (WP - 1) * C : 0) + c] = 0;
  }
}

// ---------------- depth-only window-3 stride-2 pool + reshape -> d_out (FLOAT32) ----------------
__global__ __launch_bounds__(256)
void pool_d_k(const unsigned short* __restrict__ xin, float* __restrict__ out,
              const unsigned char* __restrict__ oc) {
  int t = blockIdx.x * 256 + threadIdx.x;
  int c8 = t & 7, w = (t >> 3) & 127, h = (t >> 10) & 127, dp = (t >> 17) & 1;
  float mx[8];
#pragma unroll
  for (int q = 0; q < 8; ++q) mx[q] = 0.0f;
#pragma unroll
  for (int dd = 0; dd < 3; ++dd) {
    const unsigned short* p =
        xin + ((size_t)((2 * dp + dd) * HP + (h + 1)) * WP + (w + 1)) * 64 + c8 * 8;
    u32x4 v = *(const u32x4*)p;
    const unsigned short* u = (const unsigned short*)&v;
#pragma unroll
    for (int q = 0; q < 8; ++q) mx[q] = fmaxf(mx[q], bf2f(u[q]));
  }
  bool on = oc[(dp * HM + h) * WM + w] != 0;
#pragma unroll
  for (int q = 0; q < 8; ++q) {
    int c = c8 * 8 + q;
    out[((c * 2 + dp) * HM + h) * WM + w] = on ? mx[q] : 0.0f;
  }
}

extern "C" void kernel_launch(void* const* d_in, const int* in_sizes, int n_in,
                              void* d_out, int out_size, void* d_ws, size_t ws_size,
                              hipStream_t stream) {
  (void)n_in; (void)out_size; (void)ws_size;
  const float* vf = (const float*)d_in[0];
  const int* co = (const int*)d_in[1];
  int npts = in_sizes[1] / 4;

  char* ws = (char*)d_ws;
  const size_t SA = (size_t)18 * 130 * 130 * 64 * 2;  // P: 38,937,600 B
  const size_t SB = (size_t)10 * 130 * 130 * 64 * 2;  // Q: 21,632,000 B
  unsigned short* P = (unsigned short*)ws;
  unsigned short* Q = (unsigned short*)(ws + SA);
  unsigned short* R = P;  // C=32 scatter grid (19.47 MB) aliases P; dead after conv2 writes P
  unsigned char* occ0 = (unsigned char*)(ws + SA + SB);
  unsigned char* occ1 = occ0 + 16 * HM * WM;
  unsigned char* occ2 = occ1 + 8 * HM * WM;
  unsigned char* occ3 = occ2 + 4 * HM * WM;
  unsigned short* wb[8];
  {
    unsigned short* p = (unsigned short*)(occ3 + 2 * HM * WM);
    const int wsz[8] = {27 * 32 * 32, 27 * 64 * 32, 27 * 64 * 64, 27 * 64 * 64,
                        27 * 64 * 64, 27 * 64 * 64, 27 * 64 * 64, 27 * 64 * 64};
    for (int i = 0; i < 8; ++i) { wb[i] = p; p += wsz[i]; }
  }

  // scatter background (C=32 grid) + occ masks must be zero each call
  hipMemsetAsync(R, 0, (size_t)18 * 130 * 130 * 32 * 2, stream);
  hipMemsetAsync(occ0, 0, (size_t)(16 + 8 + 4 + 2) * HM * WM, stream);

  scatter_k<<<(npts + 255) / 256, 256, 0, stream>>>(vf, co, R, occ0, occ1, occ2, occ3, npts);

  {
    int tot = 27 * (32 * 32 + 64 * 32 + 6 * 64 * 64);  // 746496 = 2916*256
    wcvt_all_k<<<tot / 256, 256, 0, stream>>>(
        (const float*)d_in[3], (const float*)d_in[4], (const float*)d_in[5],
        (const float*)d_in[6], (const float*)d_in[7], (const float*)d_in[8],
        (const float*)d_in[9], (const float*)d_in[10], wb[0]);
  }

  conv_k<32, 32, 4><<<16 * 32, 512, 0, stream>>>(R, Q, wb[0], occ0, 16);  // Q: [18][..][32]
  conv_k<32, 64, 4><<<16 * 32, 512, 0, stream>>>(Q, P, wb[1], occ0, 16);  // P: [18][..][64]
  pool_sp_k<64><<<10 * HP, 256, 0, stream>>>(P, Q, occ1, 8);              // Q: [10][..][64]
  conv_k<64, 64, 4><<<8 * 32, 512, 0, stream>>>(Q, P, wb[2], occ1, 8);
  conv_k<64, 64, 4><<<8 * 32, 512, 0, stream>>>(P, Q, wb[3], occ1, 8);
  conv_k<64, 64, 4><<<8 * 32, 512, 0, stream>>>(Q, P, wb[4], occ1, 8);
  pool_sp_k<64><<<6 * HP, 256, 0, stream>>>(P, Q, occ2, 4);               // Q: [6][..][64]
  conv_k<64, 64, 2><<<4 * 64, 512, 0, stream>>>(Q, P, wb[5], occ2, 4);
  conv_k<64, 64, 2><<<4 * 64, 512, 0, stream>>>(P, Q, wb[6], occ2, 4);
  conv_k<64, 64, 2><<<4 * 64, 512, 0, stream>>>(Q, P, wb[7], occ2, 4);
  pool_d_k<<<(2 * 128 * 128 * 8) / 256, 256, 0, stream>>>(P, (float*)d_out, occ3);
}

// Round 11
// 276.625 us; speedup vs baseline: 1.0856x; 1.0856x over previous
//
#include <hip/hip_runtime.h>
#include <stdint.h>

#define DEV __device__ __forceinline__

typedef float f32x4 __attribute__((ext_vector_type(4)));
typedef short s16x8 __attribute__((ext_vector_type(8)));
typedef unsigned int u32x4 __attribute__((ext_vector_type(4)));
typedef unsigned int u32x2 __attribute__((ext_vector_type(2)));

static constexpr int HM = 128, WM = 128;   // logical H,W
static constexpr int HP = 130, WP = 130;   // padded H,W

DEV unsigned short f2bf(float f) {
  unsigned int u = __float_as_uint(f);
  return (unsigned short)((u + 0x7fffu + ((u >> 16) & 1u)) >> 16);  // RNE
}
DEV float bf2f(unsigned short s) { return __uint_as_float(((unsigned int)s) << 16); }

DEV void gll16(const void* g, void* l) {
  __builtin_amdgcn_global_load_lds((const unsigned int*)g, (unsigned int*)l, 16, 0, 0);
}
DEV void waitvmc(int n) {  // constant-folds under full unroll
  if (n == 0)      asm volatile("s_waitcnt vmcnt(0)" ::: "memory");
  else if (n == 1) asm volatile("s_waitcnt vmcnt(1)" ::: "memory");
  else if (n == 2) asm volatile("s_waitcnt vmcnt(2)" ::: "memory");
  else if (n == 3) asm volatile("s_waitcnt vmcnt(3)" ::: "memory");
  else if (n == 4) asm volatile("s_waitcnt vmcnt(4)" ::: "memory");
  else if (n == 5) asm volatile("s_waitcnt vmcnt(5)" ::: "memory");
  else if (n == 7) asm volatile("s_waitcnt vmcnt(7)" ::: "memory");
  else             asm volatile("s_waitcnt vmcnt(0)" ::: "memory");
}

// ---------------- scatter: points -> padded channels-last C=32 grid + occ masks ----------------
__global__ __launch_bounds__(256)
void scatter_k(const float* __restrict__ vf, const int* __restrict__ co,
               unsigned short* __restrict__ x,
               unsigned char* __restrict__ o0, unsigned char* __restrict__ o1,
               unsigned char* __restrict__ o2, unsigned char* __restrict__ o3,
               int npts) {
  int i = blockIdx.x * 256 + threadIdx.x;
  if (i >= npts) return;
  int d = co[i * 4 + 1], h = co[i * 4 + 2], w = co[i * 4 + 3];
  unsigned short* dst = x + (size_t)(((d + 1) * HP + (h + 1)) * WP + (w + 1)) * 32;
#pragma unroll
  for (int c = 0; c < 16; ++c) dst[c] = f2bf(vf[i * 16 + c]);  // ch 16..31 stay zero (memset)
  int hw = h * WM + w;
  o0[d * (HM * WM) + hw] = 1;
  o1[(d >> 1) * (HM * WM) + hw] = 1;
  o2[(d >> 2) * (HM * WM) + hw] = 1;
  o3[(d >> 3) * (HM * WM) + hw] = 1;
}

// ---------------- fused weight repack: f32 [co][ci][27] -> bf16 [tap][co][ci_dst] ----------------
__global__ __launch_bounds__(256)
void wcvt_all_k(const float* s0, const float* s1, const float* s2, const float* s3,
                const float* s4, const float* s5, const float* s6, const float* s7,
                unsigned short* __restrict__ dst) {
  int t = blockIdx.x * 256 + threadIdx.x;
  const int CIs[8] = {16, 32, 64, 64, 64, 64, 64, 64};
  const int CId[8] = {32, 32, 64, 64, 64, 64, 64, 64};
  const int COa[8] = {32, 64, 64, 64, 64, 64, 64, 64};
  const float* srcs[8] = {s0, s1, s2, s3, s4, s5, s6, s7};
  int start = 0;
#pragma unroll
  for (int i = 0; i < 8; ++i) {
    int sz = 27 * COa[i] * CId[i];
    if (t >= start && t < start + sz) {
      int l = t - start;
      int ci = l % CId[i];
      int r = l / CId[i];
      int cco = r % COa[i];
      int tap = r / COa[i];
      float v = (ci < CIs[i]) ? srcs[i][(cco * CIs[i] + ci) * 27 + tap] : 0.0f;
      dst[t] = f2bf(v);
    }
    start += sz;
  }
}

// ---------------- conv 3x3x3 implicit-GEMM, MFMA bf16, rolling-row pipeline (R7-exact) ----------------
template <int CI, int CO, int ROWS>
__global__ __launch_bounds__(512, 4)
void conv_k(const unsigned short* __restrict__ xin, unsigned short* __restrict__ xout,
            const unsigned short* __restrict__ wt, const unsigned char* __restrict__ occ,
            int D) {
  constexpr int SLOTS = CI / 8;      // 16B slots per voxel
  constexpr int MSK = SLOTS - 1;
  constexpr int CIB = CI / 32;       // K blocks of 32
  constexpr int NM = CO / 16;        // m-fragments
  constexpr int J = ROWS;            // voxel fragments per wave
  constexpr int XROWS = ROWS + 2;    // x window rows
  constexpr int RXI = (128 * SLOTS) / 512;     // gll instr per x row per thread (1 or 2)
  constexpr int NCW = 3 * CO * SLOTS;          // w chunks per tap-triple
  constexpr int KW = (NCW + 511) / 512;        // gll instr per w stage (wrap-dup if ragged)
  constexpr int NA = 2 * RXI + KW;             // vmcnt at kh=0
  constexpr int NB = RXI + KW;                 // vmcnt at kh=1,2 (kd<2)
  constexpr int WOFF = 3 * CO * CI;            // shorts per w buffer
  __shared__ __align__(16) unsigned short xs[XROWS * 130 * CI];
  __shared__ __align__(16) unsigned short wls[2 * WOFF];

  int nb = gridDim.x;  // divisible by 8
  int bid = blockIdx.x;
  int blk = (bid & 7) * (nb >> 3) + (bid >> 3);  // XCD-chunked swizzle (bijective)
  int tid = threadIdx.x;
  constexpr int HBLK = 128 / ROWS;
  int d = blk / HBLK, hb = blk - (blk / HBLK) * HBLK;
  int h0 = hb * ROWS;  // padded top row of x window; output padded rows h0+1..h0+ROWS
  int lane = tid & 63, wv = tid >> 6, ln = lane & 15, lg = lane >> 4;

  auto issueX = [&](int kd, int ri) {
#pragma unroll
    for (int i = 0; i < RXI; ++i) {
      int c = i * 512 + tid;                    // c over 128*SLOTS interior chunks
      int vcol = 1 + c / SLOTS;
      int sl = c - (c / SLOTS) * SLOTS;
      int v = ri * 130 + vcol;
      int ss = sl ^ (v & MSK);
      const unsigned short* g =
          xin + ((size_t)((d + kd) * HP + (h0 + ri)) * WP + vcol) * CI + ss * 8;
      gll16(g, xs + (size_t)(ri * 130 + 1) * CI + (size_t)c * 8);
    }
  };
  auto issueW = [&](int kd, int kh, unsigned short* wbuf) {
#pragma unroll
    for (int i = 0; i < KW; ++i) {
      int c = i * 512 + tid;
      if (c >= NCW) c -= NCW;  // wrap-duplicate (benign; keeps vmcnt uniform)
      int u = c / SLOTS, sl = c - (c / SLOTS) * SLOTS;
      int kw = u / CO, cc = u - kw * CO;
      int ss = sl ^ (u & MSK);
      const unsigned short* g =
          wt + ((size_t)((kd * 3 + kh) * 3 + kw) * CO + cc) * CI + ss * 8;
      gll16(g, wbuf + (size_t)c * 8);
    }
  };

  // ---- prologue ----
  // 1) output-halo zero (global stores FIRST -> oldest in vmcnt queue, folded into waits)
  {
    constexpr int CH8 = CO / 8;
    int hv = 2 * HP * WP + D * (2 * WP + 2 * HM);
    int tot8 = hv * CH8;
    int per = (tot8 + nb - 1) / nb;
    int base = blk * per, lim = base + per;
    if (lim > tot8) lim = tot8;
    for (int c = base + tid; c < lim; c += 512) {
      int i = c / CH8, sub = c - (c / CH8) * CH8;
      int p, hh, ww;
      if (i < 2 * HP * WP) {
        p = (i >= HP * WP) ? (D + 1) : 0;
        int rem = i - ((i >= HP * WP) ? HP * WP : 0);
        hh = rem / WP; ww = rem - hh * WP;
      } else {
        constexpr int PH = 2 * WP + 2 * HM;
        int j2 = i - 2 * HP * WP;
        p = j2 / PH + 1;
        int r2 = j2 - (p - 1) * PH;
        if (r2 < 2 * WP) { hh = (r2 >= WP) ? (HP - 1) : 0; ww = r2 % WP; }
        else { int r3 = r2 - 2 * WP; hh = 1 + (r3 & 127); ww = (r3 < HM) ? 0 : (WP - 1); }
      }
      *(u32x4*)(xout + ((size_t)(p * HP + hh) * WP + ww) * CO + sub * 8) = (u32x4)0u;
    }
  }
  // 2) first x rows + first w stage
  issueX(0, 0);
  issueX(0, 1);
  issueW(0, 0, wls);
  // 3) x-window halo columns (voxel cols 0,129) are always zero: ds_write once, never gll'd
  for (int t = tid; t < XROWS * 2 * SLOTS; t += 512) {
    int ri = t / (2 * SLOTS);
    int r2 = t - ri * 2 * SLOTS;
    int colv = (r2 >= SLOTS) ? 129 : 0;
    int sl = r2 & MSK;
    *(u32x4*)(xs + (size_t)(ri * 130 + colv) * CI + sl * 8) = (u32x4)0u;
  }
  // 4) occupancy mask
  float on[J];
#pragma unroll
  for (int j = 0; j < J; ++j) {
    int vox = wv * (16 * J) + j * 16 + ln;
    on[j] = occ[(d * HM + (h0 + (vox >> 7))) * WM + (vox & 127)] ? 1.0f : 0.0f;
  }
  asm volatile("s_waitcnt lgkmcnt(0)" ::: "memory");  // halo ds_writes done

  f32x4 acc[NM][J];
#pragma unroll
  for (int m = 0; m < NM; ++m)
#pragma unroll
    for (int j = 0; j < J; ++j) acc[m][j] = (f32x4)0.0f;

  // ---- 9 steps: (kd,kh), fully unrolled ----
#pragma unroll
  for (int s = 0; s < 9; ++s) {
    int kd = s / 3, kh = s - 3 * kd;
    unsigned short* wnext = wls + ((s + 1) & 1) * WOFF;
    // issue phase: refill slots freed by M(s-1), prefetch W(s+1)
    if (kh == 0) {
#pragma unroll
      for (int ri = 2; ri < XROWS; ++ri) issueX(kd, ri);
      issueW(kd, 1, wnext);
    } else if (kh == 1) {
      if (kd < 2) issueX(kd + 1, 0);
      issueW(kd, 2, wnext);
    } else {
      if (kd < 2) {
        issueX(kd + 1, 1);
        issueW(kd + 1, 0, wnext);
      }
    }
    __builtin_amdgcn_sched_barrier(0);
    // wait for M(s) deps (counted; never drains the prefetch queue mid-loop)
    if (kh == 0)      waitvmc(NA);
    else if (kh == 1) waitvmc(kd < 2 ? NB : KW);
    else              waitvmc(kd < 2 ? NB : 0);
    __builtin_amdgcn_sched_barrier(0);
    __builtin_amdgcn_s_barrier();
    __builtin_amdgcn_sched_barrier(0);
    // ---- MFMA phase ----
    const unsigned short* wc = wls + (s & 1) * WOFF;
    __builtin_amdgcn_s_setprio(1);
#pragma unroll
    for (int kw = 0; kw < 3; ++kw) {
#pragma unroll
      for (int cb = 0; cb < CIB; ++cb) {
        int slot = cb * 4 + lg;
        s16x8 a[NM], b[J];
#pragma unroll
        for (int m = 0; m < NM; ++m) {
          int u = kw * CO + m * 16 + ln;
          a[m] = *(const s16x8*)(wc + ((size_t)u * SLOTS + (slot ^ (u & MSK))) * 8);
        }
#pragma unroll
        for (int j = 0; j < J; ++j) {
          int vox = wv * (16 * J) + j * 16 + ln;
          int v = ((vox >> 7) + kh) * 130 + (vox & 127) + kw;
          b[j] = *(const s16x8*)(xs + ((size_t)v * SLOTS + (slot ^ (v & MSK))) * 8);
        }
#pragma unroll
        for (int m = 0; m < NM; ++m)
#pragma unroll
          for (int j = 0; j < J; ++j)
            acc[m][j] = __builtin_amdgcn_mfma_f32_16x16x32_bf16(a[m], b[j], acc[m][j], 0, 0, 0);
      }
    }
    __builtin_amdgcn_s_setprio(0);
    __builtin_amdgcn_sched_barrier(0);
    if (s < 8) __builtin_amdgcn_s_barrier();  // readers done before slots are re-written
  }

  // ---- epilogue: masked relu -> bf16. D-frag: col=lane&15 -> voxel, row=lg*4+r -> co ----
#pragma unroll
  for (int j = 0; j < J; ++j) {
    int vox = wv * (16 * J) + j * 16 + ln;
    int r = vox >> 7, w2 = vox & 127;
    unsigned short* dst = xout + ((size_t)((d + 1) * HP + (h0 + r + 1)) * WP + (w2 + 1)) * CO;
#pragma unroll
    for (int m = 0; m < NM; ++m) {
      unsigned short q0 = f2bf(fmaxf(acc[m][j][0], 0.0f) * on[j]);
      unsigned short q1 = f2bf(fmaxf(acc[m][j][1], 0.0f) * on[j]);
      unsigned short q2 = f2bf(fmaxf(acc[m][j][2], 0.0f) * on[j]);
      unsigned short q3 = f2bf(fmaxf(acc[m][j][3], 0.0f) * on[j]);
      u32x2 pv;
      pv.x = (unsigned int)q0 | ((unsigned int)q1 << 16);
      pv.y = (unsigned int)q2 | ((unsigned int)q3 << 16);
      *(u32x2*)&dst[m * 16 + lg * 4] = pv;
    }
  }
}

// ---------------- spatial 3x3x3 maxpool, stride (2,1,1), occ-masked, separable ----------------
template <int C>
__global__ __launch_bounds__(256)
void pool_sp_k(const unsigned short* __restrict__ xin, unsigned short* __restrict__ xout,
               const unsigned char* __restrict__ oc, int Dout) {
  constexpr int CH = C / 8;
  __shared__ __align__(16) unsigned short vm[WP * C];
  int row = blockIdx.x;
  int bh = row % HP, bdo = row / HP;
  int outRow = (bdo * HP + bh) * WP * C;
  int tid = threadIdx.x;
  if (bdo == 0 || bdo == Dout + 1 || bh == 0 || bh == HP - 1) {
    for (int i = tid; i < WP * C; i += 256) xout[outRow + i] = 0;
    return;
  }
  int dp = bdo - 1, h = bh - 1;

  for (int idx = tid; idx < WP * CH; idx += 256) {
    int w = idx / CH, c8 = idx - w * CH;
    float mx[8];
#pragma unroll
    for (int q = 0; q < 8; ++q) mx[q] = 0.0f;
#pragma unroll
    for (int dd = 0; dd < 3; ++dd)
#pragma unroll
      for (int hh = 0; hh < 3; ++hh) {
        const unsigned short* p =
            xin + ((size_t)((2 * dp + dd) * HP + (h + hh)) * WP + w) * C + c8 * 8;
        u32x4 v = *(const u32x4*)p;
        const unsigned short* u = (const unsigned short*)&v;
#pragma unroll
        for (int q = 0; q < 8; ++q) mx[q] = fmaxf(mx[q], bf2f(u[q]));
      }
    unsigned short o[8];
#pragma unroll
    for (int q = 0; q < 8; ++q) o[q] = f2bf(mx[q]);
    *(u32x4*)&vm[w * C + c8 * 8] = *(const u32x4*)o;
  }
  __syncthreads();

  for (int idx = tid; idx < WM * CH; idx += 256) {
    int w = idx / CH, c8 = idx - w * CH;
    float mx[8];
#pragma unroll
    for (int q = 0; q < 8; ++q) mx[q] = 0.0f;
#pragma unroll
    for (int ww = 0; ww < 3; ++ww) {
      u32x4 v = *(const u32x4*)&vm[(w + ww) * C + c8 * 8];
      const unsigned short* u = (const unsigned short*)&v;
#pragma unroll
      for (int q = 0; q < 8; ++q) mx[q] = fmaxf(mx[q], bf2f(u[q]));
    }
    bool on = oc[(dp * HM + h) * WM + w] != 0;
    unsigned short o[8];
#pragma unroll
    for (int q = 0; q < 8; ++q) o[q] = on ? f2bf(mx[q]) : (unsigned short)0;
    *(u32x4*)(xout + outRow + (w + 1) * C + c8 * 8) = *(const u32x4*)o;
  }
  for (int i = tid; i < 2 * C; i += 256) {
    int s = i / C, c = i - (i / C) * C;
    xout[outRow + (s ? (WP - 1) * C : 0) + c] = 0;
  }
}

// ---------------- depth-only window-3 stride-2 pool + reshape -> d_out (FLOAT32) ----------------
__global__ __launch_bounds__(256)
void pool_d_k(const unsigned short* __restrict__ xin, float* __restrict__ out,
              const unsigned char* __restrict__ oc) {
  int t = blockIdx.x * 256 + threadIdx.x;
  int c8 = t & 7, w = (t >> 3) & 127, h = (t >> 10) & 127, dp = (t >> 17) & 1;
  float mx[8];
#pragma unroll
  for (int q = 0; q < 8; ++q) mx[q] = 0.0f;
#pragma unroll
  for (int dd = 0; dd < 3; ++dd) {
    const unsigned short* p =
        xin + ((size_t)((2 * dp + dd) * HP + (h + 1)) * WP + (w + 1)) * 64 + c8 * 8;
    u32x4 v = *(const u32x4*)p;
    const unsigned short* u = (const unsigned short*)&v;
#pragma unroll
    for (int q = 0; q < 8; ++q) mx[q] = fmaxf(mx[q], bf2f(u[q]));
  }
  bool on = oc[(dp * HM + h) * WM + w] != 0;
#pragma unroll
  for (int q = 0; q < 8; ++q) {
    int c = c8 * 8 + q;
    out[((c * 2 + dp) * HM + h) * WM + w] = on ? mx[q] : 0.0f;
  }
}

extern "C" void kernel_launch(void* const* d_in, const int* in_sizes, int n_in,
                              void* d_out, int out_size, void* d_ws, size_t ws_size,
                              hipStream_t stream) {
  (void)n_in; (void)out_size; (void)ws_size;
  const float* vf = (const float*)d_in[0];
  const int* co = (const int*)d_in[1];
  int npts = in_sizes[1] / 4;

  char* ws = (char*)d_ws;
  const size_t SA = (size_t)18 * 130 * 130 * 64 * 2;  // P: 38,937,600 B
  const size_t SB = (size_t)10 * 130 * 130 * 64 * 2;  // Q: 21,632,000 B
  unsigned short* P = (unsigned short*)ws;
  unsigned short* Q = (unsigned short*)(ws + SA);
  unsigned short* R = P;  // C=32 scatter grid (19.47 MB) aliases P; dead after conv2 writes P
  unsigned char* occ0 = (unsigned char*)(ws + SA + SB);
  unsigned char* occ1 = occ0 + 16 * HM * WM;
  unsigned char* occ2 = occ1 + 8 * HM * WM;
  unsigned char* occ3 = occ2 + 4 * HM * WM;
  unsigned short* wb[8];
  {
    unsigned short* p = (unsigned short*)(occ3 + 2 * HM * WM);
    const int wsz[8] = {27 * 32 * 32, 27 * 64 * 32, 27 * 64 * 64, 27 * 64 * 64,
                        27 * 64 * 64, 27 * 64 * 64, 27 * 64 * 64, 27 * 64 * 64};
    for (int i = 0; i < 8; ++i) { wb[i] = p; p += wsz[i]; }
  }

  // scatter background (C=32 grid) + occ masks must be zero each call
  hipMemsetAsync(R, 0, (size_t)18 * 130 * 130 * 32 * 2, stream);
  hipMemsetAsync(occ0, 0, (size_t)(16 + 8 + 4 + 2) * HM * WM, stream);

  scatter_k<<<(npts + 255) / 256, 256, 0, stream>>>(vf, co, R, occ0, occ1, occ2, occ3, npts);

  {
    int tot = 27 * (32 * 32 + 64 * 32 + 6 * 64 * 64);  // 746496 = 2916*256
    wcvt_all_k<<<tot / 256, 256, 0, stream>>>(
        (const float*)d_in[3], (const float*)d_in[4], (const float*)d_in[5],
        (const float*)d_in[6], (const float*)d_in[7], (const float*)d_in[8],
        (const float*)d_in[9], (const float*)d_in[10], wb[0]);
  }

  conv_k<32, 32, 4><<<16 * 32, 512, 0, stream>>>(R, Q, wb[0], occ0, 16);  // Q: [18][..][32]
  conv_k<32, 64, 4><<<16 * 32, 512, 0, stream>>>(Q, P, wb[1], occ0, 16);  // P: [18][..][64]
  pool_sp_k<64><<<10 * HP, 256, 0, stream>>>(P, Q, occ1, 8);              // Q: [10][..][64]
  conv_k<64, 64, 4><<<8 * 32, 512, 0, stream>>>(Q, P, wb[2], occ1, 8);
  conv_k<64, 64, 4><<<8 * 32, 512, 0, stream>>>(P, Q, wb[3], occ1, 8);
  conv_k<64, 64, 4><<<8 * 32, 512, 0, stream>>>(Q, P, wb[4], occ1, 8);
  pool_sp_k<64><<<6 * HP, 256, 0, stream>>>(P, Q, occ2, 4);               // Q: [6][..][64]
  conv_k<64, 64, 2><<<4 * 64, 512, 0, stream>>>(Q, P, wb[5], occ2, 4);
  conv_k<64, 64, 2><<<4 * 64, 512, 0, stream>>>(P, Q, wb[6], occ2, 4);
  conv_k<64, 64, 2><<<4 * 64, 512, 0, stream>>>(Q, P, wb[7], occ2, 4);
  pool_d_k<<<(2 * 128 * 128 * 8) / 256, 256, 0, stream>>>(P, (float*)d_out, occ3);
}

// Round 12
// 262.700 us; speedup vs baseline: 1.1431x; 1.0530x over previous
//
#include <hip/hip_runtime.h>
#include <stdint.h>

#define DEV __device__ __forceinline__

typedef float f32x4 __attribute__((ext_vector_type(4)));
typedef short s16x8 __attribute__((ext_vector_type(8)));
typedef unsigned int u32x4 __attribute__((ext_vector_type(4)));
typedef unsigned int u32x2 __attribute__((ext_vector_type(2)));

static constexpr int HM = 128, WM = 128;   // logical H,W
static constexpr int HP = 130, WP = 130;   // padded H,W

DEV unsigned short f2bf(float f) {
  unsigned int u = __float_as_uint(f);
  return (unsigned short)((u + 0x7fffu + ((u >> 16) & 1u)) >> 16);  // RNE
}
DEV float bf2f(unsigned short s) { return __uint_as_float(((unsigned int)s) << 16); }

DEV void gll16(const void* g, void* l) {
  __builtin_amdgcn_global_load_lds((const unsigned int*)g, (unsigned int*)l, 16, 0, 0);
}
DEV void waitvmc(int n) {  // constant-folds under full unroll
  if (n == 0)      asm volatile("s_waitcnt vmcnt(0)" ::: "memory");
  else if (n == 1) asm volatile("s_waitcnt vmcnt(1)" ::: "memory");
  else if (n == 2) asm volatile("s_waitcnt vmcnt(2)" ::: "memory");
  else if (n == 3) asm volatile("s_waitcnt vmcnt(3)" ::: "memory");
  else if (n == 4) asm volatile("s_waitcnt vmcnt(4)" ::: "memory");
  else if (n == 5) asm volatile("s_waitcnt vmcnt(5)" ::: "memory");
  else if (n == 7) asm volatile("s_waitcnt vmcnt(7)" ::: "memory");
  else             asm volatile("s_waitcnt vmcnt(0)" ::: "memory");
}

// ---------------- scatter: points -> padded channels-last C=32 grid + occ masks ----------------
__global__ __launch_bounds__(256)
void scatter_k(const float* __restrict__ vf, const int* __restrict__ co,
               unsigned short* __restrict__ x,
               unsigned char* __restrict__ o0, unsigned char* __restrict__ o1,
               unsigned char* __restrict__ o2, unsigned char* __restrict__ o3,
               int npts) {
  int i = blockIdx.x * 256 + threadIdx.x;
  if (i >= npts) return;
  int d = co[i * 4 + 1], h = co[i * 4 + 2], w = co[i * 4 + 3];
  unsigned short* dst = x + (size_t)(((d + 1) * HP + (h + 1)) * WP + (w + 1)) * 32;
#pragma unroll
  for (int c = 0; c < 16; ++c) dst[c] = f2bf(vf[i * 16 + c]);  // ch 16..31 stay zero (memset)
  int hw = h * WM + w;
  o0[d * (HM * WM) + hw] = 1;
  o1[(d >> 1) * (HM * WM) + hw] = 1;
  o2[(d >> 2) * (HM * WM) + hw] = 1;
  o3[(d >> 3) * (HM * WM) + hw] = 1;
}

// ---------------- fused weight repack: f32 [co][ci][27] -> bf16 [tap][co][ci_dst] ----------------
__global__ __launch_bounds__(256)
void wcvt_all_k(const float* s0, const float* s1, const float* s2, const float* s3,
                const float* s4, const float* s5, const float* s6, const float* s7,
                unsigned short* __restrict__ dst) {
  int t = blockIdx.x * 256 + threadIdx.x;
  const int CIs[8] = {16, 32, 64, 64, 64, 64, 64, 64};
  const int CId[8] = {32, 32, 64, 64, 64, 64, 64, 64};
  const int COa[8] = {32, 64, 64, 64, 64, 64, 64, 64};
  const float* srcs[8] = {s0, s1, s2, s3, s4, s5, s6, s7};
  int start = 0;
#pragma unroll
  for (int i = 0; i < 8; ++i) {
    int sz = 27 * COa[i] * CId[i];
    if (t >= start && t < start + sz) {
      int l = t - start;
      int ci = l % CId[i];
      int r = l / CId[i];
      int cco = r % COa[i];
      int tap = r / COa[i];
      float v = (ci < CIs[i]) ? srcs[i][(cco * CIs[i] + ci) * 27 + tap] : 0.0f;
      dst[t] = f2bf(v);
    }
    start += sz;
  }
}

// ---------------- conv 3x3x3 implicit-GEMM, MFMA bf16, rolling-row pipeline (R7-exact) ----------------
template <int CI, int CO, int ROWS>
__global__ __launch_bounds__(512, 4)
void conv_k(const unsigned short* __restrict__ xin, unsigned short* __restrict__ xout,
            const unsigned short* __restrict__ wt, const unsigned char* __restrict__ occ,
            int D) {
  constexpr int SLOTS = CI / 8;      // 16B slots per voxel
  constexpr int MSK = SLOTS - 1;
  constexpr int CIB = CI / 32;       // K blocks of 32
  constexpr int NM = CO / 16;        // m-fragments
  constexpr int J = ROWS;            // voxel fragments per wave
  constexpr int XROWS = ROWS + 2;    // x window rows
  constexpr int RXI = (128 * SLOTS) / 512;     // gll instr per x row per thread (1 or 2)
  constexpr int NCW = 3 * CO * SLOTS;          // w chunks per tap-triple
  constexpr int KW = (NCW + 511) / 512;        // gll instr per w stage (wrap-dup if ragged)
  constexpr int NA = 2 * RXI + KW;             // vmcnt at kh=0
  constexpr int NB = RXI + KW;                 // vmcnt at kh=1,2 (kd<2)
  constexpr int WOFF = 3 * CO * CI;            // shorts per w buffer
  __shared__ __align__(16) unsigned short xs[XROWS * 130 * CI];
  __shared__ __align__(16) unsigned short wls[2 * WOFF];

  int nb = gridDim.x;  // divisible by 8
  int bid = blockIdx.x;
  int blk = (bid & 7) * (nb >> 3) + (bid >> 3);  // XCD-chunked swizzle (bijective)
  int tid = threadIdx.x;
  constexpr int HBLK = 128 / ROWS;
  int d = blk / HBLK, hb = blk - (blk / HBLK) * HBLK;
  int h0 = hb * ROWS;  // padded top row of x window; output padded rows h0+1..h0+ROWS
  int lane = tid & 63, wv = tid >> 6, ln = lane & 15, lg = lane >> 4;

  auto issueX = [&](int kd, int ri) {
#pragma unroll
    for (int i = 0; i < RXI; ++i) {
      int c = i * 512 + tid;                    // c over 128*SLOTS interior chunks
      int vcol = 1 + c / SLOTS;
      int sl = c - (c / SLOTS) * SLOTS;
      int v = ri * 130 + vcol;
      int ss = sl ^ (v & MSK);
      const unsigned short* g =
          xin + ((size_t)((d + kd) * HP + (h0 + ri)) * WP + vcol) * CI + ss * 8;
      gll16(g, xs + (size_t)(ri * 130 + 1) * CI + (size_t)c * 8);
    }
  };
  auto issueW = [&](int kd, int kh, unsigned short* wbuf) {
#pragma unroll
    for (int i = 0; i < KW; ++i) {
      int c = i * 512 + tid;
      if (c >= NCW) c -= NCW;  // wrap-duplicate (benign; keeps vmcnt uniform)
      int u = c / SLOTS, sl = c - (c / SLOTS) * SLOTS;
      int kw = u / CO, cc = u - kw * CO;
      int ss = sl ^ (u & MSK);
      const unsigned short* g =
          wt + ((size_t)((kd * 3 + kh) * 3 + kw) * CO + cc) * CI + ss * 8;
      gll16(g, wbuf + (size_t)c * 8);
    }
  };

  // ---- prologue ----
  // 1) output-halo zero (global stores FIRST -> oldest in vmcnt queue, folded into waits)
  {
    constexpr int CH8 = CO / 8;
    int hv = 2 * HP * WP + D * (2 * WP + 2 * HM);
    int tot8 = hv * CH8;
    int per = (tot8 + nb - 1) / nb;
    int base = blk * per, lim = base + per;
    if (lim > tot8) lim = tot8;
    for (int c = base + tid; c < lim; c += 512) {
      int i = c / CH8, sub = c - (c / CH8) * CH8;
      int p, hh, ww;
      if (i < 2 * HP * WP) {
        p = (i >= HP * WP) ? (D + 1) : 0;
        int rem = i - ((i >= HP * WP) ? HP * WP : 0);
        hh = rem / WP; ww = rem - hh * WP;
      } else {
        constexpr int PH = 2 * WP + 2 * HM;
        int j2 = i - 2 * HP * WP;
        p = j2 / PH + 1;
        int r2 = j2 - (p - 1) * PH;
        if (r2 < 2 * WP) { hh = (r2 >= WP) ? (HP - 1) : 0; ww = r2 % WP; }
        else { int r3 = r2 - 2 * WP; hh = 1 + (r3 & 127); ww = (r3 < HM) ? 0 : (WP - 1); }
      }
      *(u32x4*)(xout + ((size_t)(p * HP + hh) * WP + ww) * CO + sub * 8) = (u32x4)0u;
    }
  }
  // 2) first x rows + first w stage
  issueX(0, 0);
  issueX(0, 1);
  issueW(0, 0, wls);
  // 3) x-window halo columns (voxel cols 0,129) are always zero: ds_write once, never gll'd
  for (int t = tid; t < XROWS * 2 * SLOTS; t += 512) {
    int ri = t / (2 * SLOTS);
    int r2 = t - ri * 2 * SLOTS;
    int colv = (r2 >= SLOTS) ? 129 : 0;
    int sl = r2 & MSK;
    *(u32x4*)(xs + (size_t)(ri * 130 + colv) * CI + sl * 8) = (u32x4)0u;
  }
  // 4) occupancy mask
  float on[J];
#pragma unroll
  for (int j = 0; j < J; ++j) {
    int vox = wv * (16 * J) + j * 16 + ln;
    on[j] = occ[(d * HM + (h0 + (vox >> 7))) * WM + (vox & 127)] ? 1.0f : 0.0f;
  }
  asm volatile("s_waitcnt lgkmcnt(0)" ::: "memory");  // halo ds_writes done

  f32x4 acc[NM][J];
#pragma unroll
  for (int m = 0; m < NM; ++m)
#pragma unroll
    for (int j = 0; j < J; ++j) acc[m][j] = (f32x4)0.0f;

  // ---- 9 steps: (kd,kh), fully unrolled ----
#pragma unroll
  for (int s = 0; s < 9; ++s) {
    int kd = s / 3, kh = s - 3 * kd;
    unsigned short* wnext = wls + ((s + 1) & 1) * WOFF;
    // issue phase: refill slots freed by M(s-1), prefetch W(s+1)
    if (kh == 0) {
#pragma unroll
      for (int ri = 2; ri < XROWS; ++ri) issueX(kd, ri);
      issueW(kd, 1, wnext);
    } else if (kh == 1) {
      if (kd < 2) issueX(kd + 1, 0);
      issueW(kd, 2, wnext);
    } else {
      if (kd < 2) {
        issueX(kd + 1, 1);
        issueW(kd + 1, 0, wnext);
      }
    }
    __builtin_amdgcn_sched_barrier(0);
    // wait for M(s) deps (counted; never drains the prefetch queue mid-loop)
    if (kh == 0)      waitvmc(NA);
    else if (kh == 1) waitvmc(kd < 2 ? NB : KW);
    else              waitvmc(kd < 2 ? NB : 0);
    __builtin_amdgcn_sched_barrier(0);
    __builtin_amdgcn_s_barrier();
    __builtin_amdgcn_sched_barrier(0);
    // ---- MFMA phase ----
    const unsigned short* wc = wls + (s & 1) * WOFF;
    __builtin_amdgcn_s_setprio(1);
#pragma unroll
    for (int kw = 0; kw < 3; ++kw) {
#pragma unroll
      for (int cb = 0; cb < CIB; ++cb) {
        int slot = cb * 4 + lg;
        s16x8 a[NM], b[J];
#pragma unroll
        for (int m = 0; m < NM; ++m) {
          int u = kw * CO + m * 16 + ln;
          a[m] = *(const s16x8*)(wc + ((size_t)u * SLOTS + (slot ^ (u & MSK))) * 8);
        }
#pragma unroll
        for (int j = 0; j < J; ++j) {
          int vox = wv * (16 * J) + j * 16 + ln;
          int v = ((vox >> 7) + kh) * 130 + (vox & 127) + kw;
          b[j] = *(const s16x8*)(xs + ((size_t)v * SLOTS + (slot ^ (v & MSK))) * 8);
        }
#pragma unroll
        for (int m = 0; m < NM; ++m)
#pragma unroll
          for (int j = 0; j < J; ++j)
            acc[m][j] = __builtin_amdgcn_mfma_f32_16x16x32_bf16(a[m], b[j], acc[m][j], 0, 0, 0);
      }
    }
    __builtin_amdgcn_s_setprio(0);
    __builtin_amdgcn_sched_barrier(0);
    if (s < 8) __builtin_amdgcn_s_barrier();  // readers done before slots are re-written
  }

  // ---- epilogue: masked relu -> bf16. D-frag: col=lane&15 -> voxel, row=lg*4+r -> co ----
#pragma unroll
  for (int j = 0; j < J; ++j) {
    int vox = wv * (16 * J) + j * 16 + ln;
    int r = vox >> 7, w2 = vox & 127;
    unsigned short* dst = xout + ((size_t)((d + 1) * HP + (h0 + r + 1)) * WP + (w2 + 1)) * CO;
#pragma unroll
    for (int m = 0; m < NM; ++m) {
      unsigned short q0 = f2bf(fmaxf(acc[m][j][0], 0.0f) * on[j]);
      unsigned short q1 = f2bf(fmaxf(acc[m][j][1], 0.0f) * on[j]);
      unsigned short q2 = f2bf(fmaxf(acc[m][j][2], 0.0f) * on[j]);
      unsigned short q3 = f2bf(fmaxf(acc[m][j][3], 0.0f) * on[j]);
      u32x2 pv;
      pv.x = (unsigned int)q0 | ((unsigned int)q1 << 16);
      pv.y = (unsigned int)q2 | ((unsigned int)q3 << 16);
      *(u32x2*)&dst[m * 16 + lg * 4] = pv;
    }
  }
}

// ---------------- spatial 3x3x3 maxpool, stride (2,1,1): (ROWS x 64) tiles + d-max LDS ----------------
// Block = (dp, ROWS output rows, 64-wide half). Phase 1: dm[(ROWS+2)][66][C] = depth-max (each
// input row-segment read once per block; 1.5x h-overlap at ROWS=4). Phase 2: 3x3 spatial max
// from LDS + occ mask. Grid = Dout*(128/ROWS)*2 = 512 for both pools (>=2 blocks/CU; fixes
// R9's 1-wave/SIMD regression). Output halo planes/rows zeroed via per-block slices
// (R9-verified); interior halo cols unread downstream (conv zero-fills its LDS halo cols).
template <int C, int ROWS>
__global__ __launch_bounds__(256)
void pool_sp_k(const unsigned short* __restrict__ xin, unsigned short* __restrict__ xout,
               const unsigned char* __restrict__ oc, int Dout) {
  constexpr int CH = C / 8;
  constexpr int WR = ROWS + 2;                 // window rows
  __shared__ __align__(16) unsigned short dm[WR * 66 * C];
  int nb = gridDim.x;  // divisible by 8
  int bid = blockIdx.x;
  int blk = (bid & 7) * (nb >> 3) + (bid >> 3);  // XCD swizzle (bijective)
  int tid = threadIdx.x;
  constexpr int HT = 128 / ROWS;
  int wh = blk & 1;
  int rest = blk >> 1;
  int ht = rest % HT, dp = rest / HT;
  int h0 = ht * ROWS;   // logical output rows h0..h0+ROWS-1; padded input rows h0..h0+WR-1
  int w0 = wh * 64;     // logical output cols w0..w0+63; padded input cols w0..w0+65

  // output-halo zero slice (planes 0/Dout+1 full; rows 0,129 of interior planes)
  {
    int hv = 2 * HP * WP + Dout * 2 * WP;
    int tot8 = hv * CH;
    int per = (tot8 + nb - 1) / nb;
    int base = blk * per, lim = base + per;
    if (lim > tot8) lim = tot8;
    for (int c = base + tid; c < lim; c += 256) {
      int i = c / CH, sub = c - (c / CH) * CH;
      int p, hh, ww;
      if (i < 2 * HP * WP) {
        p = (i >= HP * WP) ? (Dout + 1) : 0;
        int rem = i - ((i >= HP * WP) ? HP * WP : 0);
        hh = rem / WP; ww = rem - hh * WP;
      } else {
        int j2 = i - 2 * HP * WP;
        p = j2 / (2 * WP) + 1;
        int r2 = j2 - (p - 1) * (2 * WP);
        hh = (r2 >= WP) ? (HP - 1) : 0;
        ww = r2 % WP;
      }
      *(u32x4*)(xout + ((size_t)(p * HP + hh) * WP + ww) * C + sub * 8) = (u32x4)0u;
    }
  }

  // phase 1: depth max per window row (each input 16B chunk read exactly once per block)
  for (int idx = tid; idx < WR * 66 * CH; idx += 256) {
    int ri = idx / (66 * CH);
    int rem = idx - ri * (66 * CH);
    int wc = rem / CH, c8 = rem - wc * CH;
    float mx[8];
#pragma unroll
    for (int q = 0; q < 8; ++q) mx[q] = 0.0f;
#pragma unroll
    for (int dd = 0; dd < 3; ++dd) {
      const unsigned short* p =
          xin + ((size_t)((2 * dp + dd) * HP + (h0 + ri)) * WP + (w0 + wc)) * C + c8 * 8;
      u32x4 v = *(const u32x4*)p;
      const unsigned short* u = (const unsigned short*)&v;
#pragma unroll
      for (int q = 0; q < 8; ++q) mx[q] = fmaxf(mx[q], bf2f(u[q]));
    }
    unsigned short o[8];
#pragma unroll
    for (int q = 0; q < 8; ++q) o[q] = f2bf(mx[q]);  // exact: max of bf16 values
    *(u32x4*)&dm[(size_t)(ri * 66 + wc) * C + c8 * 8] = *(const u32x4*)o;
  }
  __syncthreads();

  // phase 2: 3x3 spatial max + occ mask + coalesced store
  for (int idx = tid; idx < ROWS * 64 * CH; idx += 256) {
    int r = idx / (64 * CH);
    int rem = idx - r * (64 * CH);
    int wc2 = rem / CH, c8 = rem - wc2 * CH;
    float mx[8];
#pragma unroll
    for (int q = 0; q < 8; ++q) mx[q] = 0.0f;
#pragma unroll
    for (int rr = 0; rr < 3; ++rr)
#pragma unroll
      for (int ww = 0; ww < 3; ++ww) {
        u32x4 v = *(const u32x4*)&dm[(size_t)((r + rr) * 66 + (wc2 + ww)) * C + c8 * 8];
        const unsigned short* u = (const unsigned short*)&v;
#pragma unroll
        for (int q = 0; q < 8; ++q) mx[q] = fmaxf(mx[q], bf2f(u[q]));
      }
    bool onv = oc[(dp * HM + (h0 + r)) * WM + (w0 + wc2)] != 0;
    unsigned short o[8];
#pragma unroll
    for (int q = 0; q < 8; ++q) o[q] = onv ? f2bf(mx[q]) : (unsigned short)0;
    *(u32x4*)(xout + ((size_t)((dp + 1) * HP + (h0 + r + 1)) * WP + (w0 + wc2 + 1)) * C +
              c8 * 8) = *(const u32x4*)o;
  }
}

// ---------------- depth-only window-3 stride-2 pool + reshape -> d_out (FLOAT32) ----------------
__global__ __launch_bounds__(256)
void pool_d_k(const unsigned short* __restrict__ xin, float* __restrict__ out,
              const unsigned char* __restrict__ oc) {
  int t = blockIdx.x * 256 + threadIdx.x;
  int c8 = t & 7, w = (t >> 3) & 127, h = (t >> 10) & 127, dp = (t >> 17) & 1;
  float mx[8];
#pragma unroll
  for (int q = 0; q < 8; ++q) mx[q] = 0.0f;
#pragma unroll
  for (int dd = 0; dd < 3; ++dd) {
    const unsigned short* p =
        xin + ((size_t)((2 * dp + dd) * HP + (h + 1)) * WP + (w + 1)) * 64 + c8 * 8;
    u32x4 v = *(const u32x4*)p;
    const unsigned short* u = (const unsigned short*)&v;
#pragma unroll
    for (int q = 0; q < 8; ++q) mx[q] = fmaxf(mx[q], bf2f(u[q]));
  }
  bool on = oc[(dp * HM + h) * WM + w] != 0;
#pragma unroll
  for (int q = 0; q < 8; ++q) {
    int c = c8 * 8 + q;
    out[((c * 2 + dp) * HM + h) * WM + w] = on ? mx[q] : 0.0f;
  }
}

extern "C" void kernel_launch(void* const* d_in, const int* in_sizes, int n_in,
                              void* d_out, int out_size, void* d_ws, size_t ws_size,
                              hipStream_t stream) {
  (void)n_in; (void)out_size; (void)ws_size;
  const float* vf = (const float*)d_in[0];
  const int* co = (const int*)d_in[1];
  int npts = in_sizes[1] / 4;

  char* ws = (char*)d_ws;
  const size_t SA = (size_t)18 * 130 * 130 * 64 * 2;  // P: 38,937,600 B
  const size_t SB = (size_t)10 * 130 * 130 * 64 * 2;  // Q: 21,632,000 B
  unsigned short* P = (unsigned short*)ws;
  unsigned short* Q = (unsigned short*)(ws + SA);
  unsigned short* R = P;  // C=32 scatter grid (19.47 MB) aliases P; dead after conv2 writes P
  unsigned char* occ0 = (unsigned char*)(ws + SA + SB);
  unsigned char* occ1 = occ0 + 16 * HM * WM;
  unsigned char* occ2 = occ1 + 8 * HM * WM;
  unsigned char* occ3 = occ2 + 4 * HM * WM;
  unsigned short* wb[8];
  {
    unsigned short* p = (unsigned short*)(occ3 + 2 * HM * WM);
    const int wsz[8] = {27 * 32 * 32, 27 * 64 * 32, 27 * 64 * 64, 27 * 64 * 64,
                        27 * 64 * 64, 27 * 64 * 64, 27 * 64 * 64, 27 * 64 * 64};
    for (int i = 0; i < 8; ++i) { wb[i] = p; p += wsz[i]; }
  }

  // scatter background (C=32 grid) + occ masks must be zero each call
  hipMemsetAsync(R, 0, (size_t)18 * 130 * 130 * 32 * 2, stream);
  hipMemsetAsync(occ0, 0, (size_t)(16 + 8 + 4 + 2) * HM * WM, stream);

  scatter_k<<<(npts + 255) / 256, 256, 0, stream>>>(vf, co, R, occ0, occ1, occ2, occ3, npts);

  {
    int tot = 27 * (32 * 32 + 64 * 32 + 6 * 64 * 64);  // 746496 = 2916*256
    wcvt_all_k<<<tot / 256, 256, 0, stream>>>(
        (const float*)d_in[3], (const float*)d_in[4], (const float*)d_in[5],
        (const float*)d_in[6], (const float*)d_in[7], (const float*)d_in[8],
        (const float*)d_in[9], (const float*)d_in[10], wb[0]);
  }

  conv_k<32, 32, 4><<<16 * 32, 512, 0, stream>>>(R, Q, wb[0], occ0, 16);  // Q: [18][..][32]
  conv_k<32, 64, 4><<<16 * 32, 512, 0, stream>>>(Q, P, wb[1], occ0, 16);  // P: [18][..][64]
  pool_sp_k<64, 4><<<8 * 32 * 2, 256, 0, stream>>>(P, Q, occ1, 8);        // Q: [10][..][64]
  conv_k<64, 64, 4><<<8 * 32, 512, 0, stream>>>(Q, P, wb[2], occ1, 8);
  conv_k<64, 64, 4><<<8 * 32, 512, 0, stream>>>(P, Q, wb[3], occ1, 8);
  conv_k<64, 64, 4><<<8 * 32, 512, 0, stream>>>(Q, P, wb[4], occ1, 8);
  pool_sp_k<64, 2><<<4 * 64 * 2, 256, 0, stream>>>(P, Q, occ2, 4);        // Q: [6][..][64]
  conv_k<64, 64, 2><<<4 * 64, 512, 0, stream>>>(Q, P, wb[5], occ2, 4);
  conv_k<64, 64, 2><<<4 * 64, 512, 0, stream>>>(P, Q, wb[6], occ2, 4);
  conv_k<64, 64, 2><<<4 * 64, 512, 0, stream>>>(Q, P, wb[7], occ2, 4);
  pool_d_k<<<(2 * 128 * 128 * 8) / 256, 256, 0, stream>>>(P, (float*)d_out, occ3);
}